// Round 16
// baseline (151.017 us; speedup 1.0000x reference)
//
#include <hip/hip_runtime.h>

#define B_    1024
#define AB_   6
#define BIN_  16
#define BOUT_ 32

typedef float f4 __attribute__((ext_vector_type(4)));
typedef _Float16 hlf4 __attribute__((ext_vector_type(4)));

// out[slice, o, l, k] = sum_i X[slice, i, l] * W[ab, i, o, k]
//
// R16: MFMA. R14+arithmetic: R9's l8 body is VALU-ISSUE-bound (816 VALU
// ops/thread = 49us computed vs 51.7 measured). Per slice this is a GEMM:
// M = l (NSH), N = (o,k) flat (32*NSH), K = i (16) -> ONE
// v_mfma_f32_16x16x16_f16 per 16x16 tile (K=16=BIN, no acc chain).
// fp16 in / fp32 acc: worst-case err ~9e-3 << 2.78e-2 threshold.
//
// Fragment layouts (guide §3, m89-verified): A: row=lane&15, k=(lane>>4)*4+j;
// B: col=lane&15, same k; D: col=lane&15, row=(lane>>4)*4+j.
// N=(o,k) flat = o*NSH+k means: B(=W) loads at [i*32*NSH + n] are coalesced;
// D cols n are k-contiguous dwords -> stores land in 64B runs (4 row-segments
// per instr). Only store addressing needs n/NSH (magic mul).
// B-frags (W) hoisted per wave and reused across SPW slices; A-frags (X) are
// 2 coalesced loads per slice. No LDS, no syncthreads.
template<int NSH, int SPW>
__global__ __launch_bounds__(256)
void conv_mfma(const float* __restrict__ X, const float* __restrict__ W,
               float* __restrict__ OUT) {
    constexpr int SZ   = BIN_ * NSH;
    constexpr int NOUT = BOUT_ * NSH * NSH;
    constexpr int NT   = (BOUT_ * NSH) / 16;   // N-tiles (32*NSH % 16 == 0)
    constexpr int MT   = (NSH + 15) / 16;      // M-tiles (tail rows masked)

    const int lane = threadIdx.x & 63;
    const int w    = threadIdx.x >> 6;
    const int lm   = lane & 15;                // A-row / B-col / D-col
    const int lk   = (lane >> 4) * 4;          // A/B k-chunk; D row-chunk

    const int ab = blockIdx.x % AB_;
    const int g  = blockIdx.x / AB_;
    const int t0 = (g * 4 + w) * SPW;          // slice = ab + 6*t

    const float* Wab = W + (size_t)ab * (BIN_ * BOUT_ * NSH);

    // ---- hoist B-frags (W): B[k=lk+j][n=ni*16+lm]; loads coalesced in n ----
    hlf4 bfrag[NT];
#pragma unroll
    for (int ni = 0; ni < NT; ++ni) {
        const int n = ni * 16 + lm;
#pragma unroll
        for (int j = 0; j < 4; ++j)
            bfrag[ni][j] = (_Float16)Wab[(lk + j) * (BOUT_ * NSH) + n];
    }

    for (int s = 0; s < SPW; ++s) {
        const int slice = ab + AB_ * (t0 + s);
        const float* Xs = X + (size_t)slice * SZ;
        float* Os = OUT + (size_t)slice * NOUT;

        // ---- A-frags (X^T): A[row=l][k=lk+j] = X[lk+j][l]; coalesced in l ----
        hlf4 afrag[MT];
#pragma unroll
        for (int mi = 0; mi < MT; ++mi) {
            const int l  = mi * 16 + lm;
            const int lc = (l > NSH - 1) ? (NSH - 1) : l;   // clamp, masked later
#pragma unroll
            for (int j = 0; j < 4; ++j)
                afrag[mi][j] = (_Float16)Xs[(lk + j) * NSH + lc];
        }

#pragma unroll
        for (int ni = 0; ni < NT; ++ni) {
            const int n = ni * 16 + lm;
            const int o = n / NSH;              // magic-mul (constexpr NSH)
            const int kq = n - o * NSH;
            float* base = Os + o * (NSH * NSH) + kq;
#pragma unroll
            for (int mi = 0; mi < MT; ++mi) {
                f4 d = __builtin_amdgcn_mfma_f32_16x16x16f16(
                    afrag[mi], bfrag[ni], (f4){0.f, 0.f, 0.f, 0.f}, 0, 0, 0);
#pragma unroll
                for (int j = 0; j < 4; ++j) {
                    const int l = mi * 16 + lk + j;   // D row
                    if (l < NSH) base[l * NSH] = d[j];
                }
            }
        }
    }
}

// l=0: direct coalesced stores, 64 n per block (unchanged, ~1.5us).
__global__ __launch_bounds__(256)
void conv_l0_kernel(const float* __restrict__ X, const float* __restrict__ W,
                    const float* __restrict__ bias, float* __restrict__ OUT) {
    const int o  = threadIdx.x & 31;
    const int ns = threadIdx.x >> 5;   // 0..7
    const int b  = blockIdx.x;
    const int n0 = (b / AB_) * 64;
    const int ab = b % AB_;
    float wv[BIN_];
#pragma unroll
    for (int i = 0; i < BIN_; ++i) wv[i] = W[(ab * BIN_ + i) * BOUT_ + o];
    const float bv = bias[ab * BOUT_ + o];
#pragma unroll
    for (int s = 0; s < 8; ++s) {
        const int n = n0 + ns + s * 8;
        const float* Xp = X + ((size_t)n * AB_ + ab) * BIN_;
        float acc = bv;
#pragma unroll
        for (int i = 0; i < BIN_; ++i) acc = fmaf(Xp[i], wv[i], acc);
        OUT[((size_t)n * AB_ + ab) * BOUT_ + o] = acc;
    }
}

extern "C" void kernel_launch(void* const* d_in, const int* in_sizes, int n_in,
                              void* d_out, int out_size, void* d_ws, size_t ws_size,
                              hipStream_t stream) {
    const float* x0 = (const float*)d_in[0];
    const float* w0 = (const float*)d_in[1];
    const float* x2 = (const float*)d_in[2];
    const float* w2 = (const float*)d_in[3];
    const float* x4 = (const float*)d_in[4];
    const float* w4 = (const float*)d_in[5];
    const float* x6 = (const float*)d_in[6];
    const float* w6 = (const float*)d_in[7];
    const float* x8 = (const float*)d_in[8];
    const float* w8 = (const float*)d_in[9];
    const float* bias = (const float*)d_in[10];
    float* out = (float*)d_out;

    const size_t per = (size_t)B_ * AB_ * BOUT_;
    size_t off0 = 0;
    size_t off2 = off0 + per * 1;
    size_t off4 = off2 + per * 25;
    size_t off6 = off4 + per * 81;
    size_t off8 = off6 + per * 169;

    // 256 thr = 4 waves/block; each wave = SPW slices; 6144/(4*SPW) blocks.
    //         NSH SPW               grid
    conv_mfma<17, 2><<<768, 256, 0, stream>>>(x8, w8, out + off8);
    conv_mfma<13, 2><<<768, 256, 0, stream>>>(x6, w6, out + off6);
    conv_mfma< 9, 2><<<768, 256, 0, stream>>>(x4, w4, out + off4);
    conv_mfma< 5, 2><<<768, 256, 0, stream>>>(x2, w2, out + off2);
    conv_l0_kernel<<<(B_ / 64) * AB_, 256, 0, stream>>>(x0, w0, bias, out + off0);
}

// Round 17
// 136.837 us; speedup vs baseline: 1.1036x; 1.1036x over previous
//
#include <hip/hip_runtime.h>

#define B_    1024
#define AB_   6
#define BIN_  16
#define BOUT_ 32

typedef float f4 __attribute__((ext_vector_type(4)));
typedef _Float16 hlf4 __attribute__((ext_vector_type(4)));

// out[slice, o, l, k] = sum_i X[slice, i, l] * W[ab, i, o, k]
//
// R17 = R16's MFMA bodies fused into ONE launch (blockIdx-range dispatch,
// inlined). R16 proved: VALU->MFMA (8x fewer VALU ops) left the total at
// ~151 -> bodies aren't the binding constraint; the 5 serialized launches
// are (~45us of dispatch/drain/BW-ramp between kernels per R14 accounting).
// Inlined (not __noinline__, which cost R10 ~25us); MFMA branch is lean
// (no LDS, ~100 VGPR) so shared regalloc shouldn't collapse (R2's failure
// was a VALU body needing 115+ VGPRs squeezed to 60).
//
// Body per degree (R16, verified absmax 7.8e-3): per-slice GEMM
// M=l (NSH), N=(o,k) flat, K=i=16 -> one v_mfma_f32_16x16x16_f16 per tile.
// A[row=l, k=i] from X^T (coalesced in l); B[k=i, col=n] from W (coalesced
// in n); D col=n, row=l -> stores land as 4x64B segments per instr.
// B-frags hoisted per wave, reused over SPW slices.
template<int NSH, int SPW>
__device__ __forceinline__ void mfma_body(const float* __restrict__ X,
                                          const float* __restrict__ W,
                                          float* __restrict__ OUT, int bi) {
    constexpr int SZ   = BIN_ * NSH;
    constexpr int NOUT = BOUT_ * NSH * NSH;
    constexpr int NT   = (BOUT_ * NSH) / 16;   // N-tiles
    constexpr int MT   = (NSH + 15) / 16;      // M-tiles (tail rows masked)

    const int lane = threadIdx.x & 63;
    const int w    = threadIdx.x >> 6;
    const int lm   = lane & 15;                // A-row / B-col / D-col
    const int lk   = (lane >> 4) * 4;          // A/B k-chunk; D row-chunk

    const int ab = bi % AB_;
    const int g  = bi / AB_;
    const int t0 = (g * 4 + w) * SPW;          // slice = ab + 6*t

    const float* Wab = W + (size_t)ab * (BIN_ * BOUT_ * NSH);

    // hoist B-frags (W): B[k=lk+j][n=ni*16+lm]; loads coalesced in n
    hlf4 bfrag[NT];
#pragma unroll
    for (int ni = 0; ni < NT; ++ni) {
        const int n = ni * 16 + lm;
#pragma unroll
        for (int j = 0; j < 4; ++j)
            bfrag[ni][j] = (_Float16)Wab[(lk + j) * (BOUT_ * NSH) + n];
    }

    for (int s = 0; s < SPW; ++s) {
        const int slice = ab + AB_ * (t0 + s);
        const float* Xs = X + (size_t)slice * SZ;
        float* Os = OUT + (size_t)slice * NOUT;

        // A-frags (X^T): A[row=l][k=lk+j] = X[lk+j][l]; coalesced in l
        hlf4 afrag[MT];
#pragma unroll
        for (int mi = 0; mi < MT; ++mi) {
            const int l  = mi * 16 + lm;
            const int lc = (l > NSH - 1) ? (NSH - 1) : l;   // clamp, masked later
#pragma unroll
            for (int j = 0; j < 4; ++j)
                afrag[mi][j] = (_Float16)Xs[(lk + j) * NSH + lc];
        }

#pragma unroll
        for (int ni = 0; ni < NT; ++ni) {
            const int n = ni * 16 + lm;
            const int o = n / NSH;              // constexpr divisor -> magic mul
            const int kq = n - o * NSH;
            float* base = Os + o * (NSH * NSH) + kq;
#pragma unroll
            for (int mi = 0; mi < MT; ++mi) {
                f4 d = __builtin_amdgcn_mfma_f32_16x16x16f16(
                    afrag[mi], bfrag[ni], (f4){0.f, 0.f, 0.f, 0.f}, 0, 0, 0);
#pragma unroll
                for (int j = 0; j < 4; ++j) {
                    const int l = mi * 16 + lk + j;   // D row
                    if (l < NSH) base[l * NSH] = d[j];
                }
            }
        }
    }
}

// l=0: direct coalesced stores, 64 n per block.
__device__ __forceinline__ void l0_body(const float* __restrict__ X,
                                        const float* __restrict__ W,
                                        const float* __restrict__ bias,
                                        float* __restrict__ OUT, int b) {
    const int o  = threadIdx.x & 31;
    const int ns = threadIdx.x >> 5;   // 0..7
    const int n0 = (b / AB_) * 64;
    const int ab = b % AB_;
    float wv[BIN_];
#pragma unroll
    for (int i = 0; i < BIN_; ++i) wv[i] = W[(ab * BIN_ + i) * BOUT_ + o];
    const float bv = bias[ab * BOUT_ + o];
#pragma unroll
    for (int s = 0; s < 8; ++s) {
        const int n = n0 + ns + s * 8;
        const float* Xp = X + ((size_t)n * AB_ + ab) * BIN_;
        float acc = bv;
#pragma unroll
        for (int i = 0; i < BIN_; ++i) acc = fmaf(Xp[i], wv[i], acc);
        OUT[((size_t)n * AB_ + ab) * BOUT_ + o] = acc;
    }
}

#define NB8 768
#define NB6 768
#define NB4 768
#define NB2 768
#define NB0 96

__global__ __launch_bounds__(256, 2)
void s2conv_one(const float* __restrict__ x0, const float* __restrict__ x2,
                const float* __restrict__ x4, const float* __restrict__ x6,
                const float* __restrict__ x8,
                const float* __restrict__ w0, const float* __restrict__ w2,
                const float* __restrict__ w4, const float* __restrict__ w6,
                const float* __restrict__ w8,
                const float* __restrict__ bias, float* __restrict__ out,
                size_t off0, size_t off2, size_t off4, size_t off6, size_t off8) {
    int b = blockIdx.x;                        // big degrees first
    if (b < NB8) { mfma_body<17, 2>(x8, w8, out + off8, b); return; }
    b -= NB8;
    if (b < NB6) { mfma_body<13, 2>(x6, w6, out + off6, b); return; }
    b -= NB6;
    if (b < NB4) { mfma_body< 9, 2>(x4, w4, out + off4, b); return; }
    b -= NB4;
    if (b < NB2) { mfma_body< 5, 2>(x2, w2, out + off2, b); return; }
    b -= NB2;
    l0_body(x0, w0, bias, out + off0, b);
}

extern "C" void kernel_launch(void* const* d_in, const int* in_sizes, int n_in,
                              void* d_out, int out_size, void* d_ws, size_t ws_size,
                              hipStream_t stream) {
    const float* x0 = (const float*)d_in[0];
    const float* w0 = (const float*)d_in[1];
    const float* x2 = (const float*)d_in[2];
    const float* w2 = (const float*)d_in[3];
    const float* x4 = (const float*)d_in[4];
    const float* w4 = (const float*)d_in[5];
    const float* x6 = (const float*)d_in[6];
    const float* w6 = (const float*)d_in[7];
    const float* x8 = (const float*)d_in[8];
    const float* w8 = (const float*)d_in[9];
    const float* bias = (const float*)d_in[10];
    float* out = (float*)d_out;

    const size_t per = (size_t)B_ * AB_ * BOUT_;
    size_t off0 = 0;
    size_t off2 = off0 + per * 1;
    size_t off4 = off2 + per * 25;
    size_t off6 = off4 + per * 81;
    size_t off8 = off6 + per * 169;

    const int nblocks = NB8 + NB6 + NB4 + NB2 + NB0;   // 3168
    s2conv_one<<<nblocks, 256, 0, stream>>>(x0, x2, x4, x6, x8,
                                            w0, w2, w4, w6, w8,
                                            bias, out,
                                            off0, off2, off4, off6, off8);
}

// Round 18
// 112.465 us; speedup vs baseline: 1.3428x; 1.2167x over previous
//
#include <hip/hip_runtime.h>

#define B_    1024
#define AB_   6
#define BIN_  16
#define BOUT_ 32

typedef float f4 __attribute__((ext_vector_type(4)));
typedef _Float16 hlf4 __attribute__((ext_vector_type(4)));

// out[slice, o, l, k] = sum_i X[slice, i, l] * W[ab, i, o, k]
//
// R18 = R17 (fused, MFMA) + DENSE LDS-staged output flush.
// Unified theory of the 150us plateau: scattered 4-16B stores run the write
// path at ~55% (R14: 3.8TB/s, nothing else saturated; partial 32B sectors),
// dense f4 streams run ~6.8TB/s (fillBuffer). Every prior kernel either
// stored scattered (R9/R16/R17) or was DS-saturated while storing dense
// (R7's X-broadcast: 4.5GB LDS reads). MFMA compute + dense flush is the
// untested cell: DS pipe carries ONLY the output tile (~888MB both ways,
// ~10us), stores leave as full 128B lines.
//
// Per slice: 4 waves cooperate. Wave w owns ceil(NT/4) N-tiles (B-frags
// <=18 VGPR). MFMA D-frags -> LDS tile (b32, <=4-way conflicts) -> sync ->
// 256-thread contiguous f4 flush -> sync. B-frags hoisted once per block
// (all SPB slices share ab). A-frags: 4B loads, coalesced in l.
template<int NSH, int SPB>
__device__ __forceinline__ void mfma_lds_body(const float* __restrict__ X,
                                              const float* __restrict__ W,
                                              float* __restrict__ OUT,
                                              float* os, int bi) {
    constexpr int SZ   = BIN_ * NSH;
    constexpr int NOUT = BOUT_ * NSH * NSH;
    constexpr int NT   = (BOUT_ * NSH) / 16;   // N-tiles
    constexpr int MT   = (NSH + 15) / 16;      // M-tiles (tail rows masked)
    constexpr int NTQ  = (NT + 3) / 4;         // N-tiles per wave

    const int tid  = threadIdx.x;
    const int lane = tid & 63;
    const int w    = tid >> 6;                 // wave 0..3
    const int lm   = lane & 15;                // A-row / B-col / D-col
    const int lk   = (lane >> 4) * 4;          // A/B k-chunk; D row-chunk

    const int ab = bi % AB_;
    const int g  = bi / AB_;

    const float* Wab = W + (size_t)ab * (BIN_ * BOUT_ * NSH);

    // ---- hoist this wave's B-frags once per block (wave-uniform count) ----
    hlf4 bfrag[NTQ];
#pragma unroll
    for (int t = 0; t < NTQ; ++t) {
        const int ni = w * NTQ + t;
        if (ni < NT) {
            const int n = ni * 16 + lm;
#pragma unroll
            for (int j = 0; j < 4; ++j)
                bfrag[t][j] = (_Float16)Wab[(lk + j) * (BOUT_ * NSH) + n];
        }
    }

    for (int s = 0; s < SPB; ++s) {
        const int slice = ab + AB_ * (g * SPB + s);
        const float* Xs = X + (size_t)slice * SZ;

        // ---- A-frags (X^T): A[row=l][k=lk+j]; coalesced in l ----
        hlf4 afrag[MT];
#pragma unroll
        for (int mi = 0; mi < MT; ++mi) {
            const int l  = mi * 16 + lm;
            const int lc = (l > NSH - 1) ? (NSH - 1) : l;   // clamp, masked later
#pragma unroll
            for (int j = 0; j < 4; ++j)
                afrag[mi][j] = (_Float16)Xs[(lk + j) * NSH + lc];
        }

        // ---- this wave's tiles -> LDS ----
#pragma unroll
        for (int t = 0; t < NTQ; ++t) {
            const int ni = w * NTQ + t;
            if (ni < NT) {
                const int n  = ni * 16 + lm;
                const int o  = n / NSH;          // constexpr divisor -> magic mul
                const int kq = n - o * NSH;
                float* base = os + o * (NSH * NSH) + kq;
#pragma unroll
                for (int mi = 0; mi < MT; ++mi) {
                    f4 d = __builtin_amdgcn_mfma_f32_16x16x16f16(
                        afrag[mi], bfrag[t], (f4){0.f, 0.f, 0.f, 0.f}, 0, 0, 0);
#pragma unroll
                    for (int j = 0; j < 4; ++j) {
                        const int l = mi * 16 + lk + j;   // D row
                        if (l < NSH) base[l * NSH] = d[j];
                    }
                }
            }
        }
        __syncthreads();

        // ---- dense contiguous f4 flush (full 128B lines out) ----
        f4* dst = (f4*)(OUT + (size_t)slice * NOUT);
        const f4* src = (const f4*)os;
        for (int c = tid; c < NOUT / 4; c += 256) dst[c] = src[c];
        __syncthreads();
    }
}

// l=0: direct coalesced stores, 64 n per block.
__device__ __forceinline__ void l0_body(const float* __restrict__ X,
                                        const float* __restrict__ W,
                                        const float* __restrict__ bias,
                                        float* __restrict__ OUT, int b) {
    const int o  = threadIdx.x & 31;
    const int ns = threadIdx.x >> 5;   // 0..7
    const int n0 = (b / AB_) * 64;
    const int ab = b % AB_;
    float wv[BIN_];
#pragma unroll
    for (int i = 0; i < BIN_; ++i) wv[i] = W[(ab * BIN_ + i) * BOUT_ + o];
    const float bv = bias[ab * BOUT_ + o];
#pragma unroll
    for (int s = 0; s < 8; ++s) {
        const int n = n0 + ns + s * 8;
        const float* Xp = X + ((size_t)n * AB_ + ab) * BIN_;
        float acc = bv;
#pragma unroll
        for (int i = 0; i < BIN_; ++i) acc = fmaf(Xp[i], wv[i], acc);
        OUT[((size_t)n * AB_ + ab) * BOUT_ + o] = acc;
    }
}

#define NB8 768   // 6144 slices / SPB 8
#define NB6 768
#define NB4 768
#define NB2 768
#define NB0 96

__global__ __launch_bounds__(256, 4)
void s2conv_one(const float* __restrict__ x0, const float* __restrict__ x2,
                const float* __restrict__ x4, const float* __restrict__ x6,
                const float* __restrict__ x8,
                const float* __restrict__ w0, const float* __restrict__ w2,
                const float* __restrict__ w4, const float* __restrict__ w6,
                const float* __restrict__ w8,
                const float* __restrict__ bias, float* __restrict__ out,
                size_t off0, size_t off2, size_t off4, size_t off6, size_t off8) {
    __shared__ __attribute__((aligned(16))) float os[BOUT_ * 17 * 17];  // 37 KB
    int b = blockIdx.x;                        // big degrees first
    if (b < NB8) { mfma_lds_body<17, 8>(x8, w8, out + off8, os, b); return; }
    b -= NB8;
    if (b < NB6) { mfma_lds_body<13, 8>(x6, w6, out + off6, os, b); return; }
    b -= NB6;
    if (b < NB4) { mfma_lds_body< 9, 8>(x4, w4, out + off4, os, b); return; }
    b -= NB4;
    if (b < NB2) { mfma_lds_body< 5, 8>(x2, w2, out + off2, os, b); return; }
    b -= NB2;
    l0_body(x0, w0, bias, out + off0, b);
}

extern "C" void kernel_launch(void* const* d_in, const int* in_sizes, int n_in,
                              void* d_out, int out_size, void* d_ws, size_t ws_size,
                              hipStream_t stream) {
    const float* x0 = (const float*)d_in[0];
    const float* w0 = (const float*)d_in[1];
    const float* x2 = (const float*)d_in[2];
    const float* w2 = (const float*)d_in[3];
    const float* x4 = (const float*)d_in[4];
    const float* w4 = (const float*)d_in[5];
    const float* x6 = (const float*)d_in[6];
    const float* w6 = (const float*)d_in[7];
    const float* x8 = (const float*)d_in[8];
    const float* w8 = (const float*)d_in[9];
    const float* bias = (const float*)d_in[10];
    float* out = (float*)d_out;

    const size_t per = (size_t)B_ * AB_ * BOUT_;
    size_t off0 = 0;
    size_t off2 = off0 + per * 1;
    size_t off4 = off2 + per * 25;
    size_t off6 = off4 + per * 81;
    size_t off8 = off6 + per * 169;

    const int nblocks = NB8 + NB6 + NB4 + NB2 + NB0;   // 3168
    s2conv_one<<<nblocks, 256, 0, stream>>>(x0, x2, x4, x6, x8,
                                            w0, w2, w4, w6, w8,
                                            bias, out,
                                            off0, off2, off4, off6, off8);
}

// Round 19
// 108.318 us; speedup vs baseline: 1.3942x; 1.0383x over previous
//
#include <hip/hip_runtime.h>

#define B_    1024
#define AB_   6
#define BIN_  16
#define BOUT_ 32

typedef float f4 __attribute__((ext_vector_type(4)));
typedef _Float16 hlf4 __attribute__((ext_vector_type(4)));

// out[slice, o, l, k] = sum_i X[slice, i, l] * W[ab, i, o, k]
//
// R19 = R18 (fused + MFMA + dense LDS flush; 112.5us) + A-frag software
// pipeline. R18 accounting: store floor ~65us; the ~45us gap = per-slice
// serial latency, dominated by A-frag global loads (8x4B, L3 ~400cy) that
// issue only after the flush barrier and stall the next MFMA phase.
// Fix: load slice s+1's A-frags BETWEEN compute-barrier and flush of s --
// their latency hides under the flush's store stream. Named cur/next
// register arrays (static indexing), register-move swap.
//
// Per slice: 4 waves cooperate; wave owns ceil(NT/4) N-tiles (B-frags
// hoisted once per block, <=18 VGPR). MFMA D -> LDS tile (b32) -> sync ->
// prefetch next A -> dense 256-thread f4 flush (full 128B lines) -> sync.
template<int NSH, int SPB>
__device__ __forceinline__ void mfma_lds_body(const float* __restrict__ X,
                                              const float* __restrict__ W,
                                              float* __restrict__ OUT,
                                              float* os, int bi) {
    constexpr int SZ   = BIN_ * NSH;
    constexpr int NOUT = BOUT_ * NSH * NSH;
    constexpr int NT   = (BOUT_ * NSH) / 16;   // N-tiles
    constexpr int MT   = (NSH + 15) / 16;      // M-tiles (tail rows masked)
    constexpr int NTQ  = (NT + 3) / 4;         // N-tiles per wave

    const int tid  = threadIdx.x;
    const int lane = tid & 63;
    const int w    = tid >> 6;                 // wave 0..3
    const int lm   = lane & 15;                // A-row / B-col / D-col
    const int lk   = (lane >> 4) * 4;          // A/B k-chunk; D row-chunk

    const int ab = bi % AB_;
    const int g  = bi / AB_;

    const float* Wab = W + (size_t)ab * (BIN_ * BOUT_ * NSH);

    // ---- hoist this wave's B-frags once per block ----
    hlf4 bfrag[NTQ];
#pragma unroll
    for (int t = 0; t < NTQ; ++t) {
        const int ni = w * NTQ + t;
        if (ni < NT) {
            const int n = ni * 16 + lm;
#pragma unroll
            for (int j = 0; j < 4; ++j)
                bfrag[t][j] = (_Float16)Wab[(lk + j) * (BOUT_ * NSH) + n];
        }
    }

    // A-frag loader: A[row=l][k=lk+j] = X[lk+j][l], coalesced in l
    const int lc = ((MT * 16 - 16 + lm) > NSH - 1) ? 0 : 0;  // (placeholder fold)
    auto load_a = [&](int slice, hlf4* dst) {
        const float* Xs = X + (size_t)slice * SZ;
#pragma unroll
        for (int mi = 0; mi < MT; ++mi) {
            const int l  = mi * 16 + lm;
            const int lcl = (l > NSH - 1) ? (NSH - 1) : l;   // clamp, masked later
#pragma unroll
            for (int j = 0; j < 4; ++j)
                dst[mi][j] = (_Float16)Xs[(lk + j) * NSH + lcl];
        }
    };
    (void)lc;

    hlf4 acur[MT], anext[MT];
    load_a(ab + AB_ * (g * SPB), acur);        // prologue

    for (int s = 0; s < SPB; ++s) {
        const int slice = ab + AB_ * (g * SPB + s);

        // ---- this wave's tiles -> LDS ----
#pragma unroll
        for (int t = 0; t < NTQ; ++t) {
            const int ni = w * NTQ + t;
            if (ni < NT) {
                const int n  = ni * 16 + lm;
                const int o  = n / NSH;          // constexpr divisor -> magic mul
                const int kq = n - o * NSH;
                float* base = os + o * (NSH * NSH) + kq;
#pragma unroll
                for (int mi = 0; mi < MT; ++mi) {
                    f4 d = __builtin_amdgcn_mfma_f32_16x16x16f16(
                        acur[mi], bfrag[t], (f4){0.f, 0.f, 0.f, 0.f}, 0, 0, 0);
#pragma unroll
                    for (int j = 0; j < 4; ++j) {
                        const int l = mi * 16 + lk + j;   // D row
                        if (l < NSH) base[l * NSH] = d[j];
                    }
                }
            }
        }
        __syncthreads();

        // ---- prefetch next slice's A-frags (latency hides under flush) ----
        if (s + 1 < SPB) load_a(slice + AB_, anext);

        // ---- dense contiguous f4 flush (full 128B lines out) ----
        f4* dst = (f4*)(OUT + (size_t)slice * NOUT);
        const f4* src = (const f4*)os;
        for (int c = tid; c < NOUT / 4; c += 256) dst[c] = src[c];
        __syncthreads();

#pragma unroll
        for (int mi = 0; mi < MT; ++mi) acur[mi] = anext[mi];
    }
}

// l=0: direct coalesced stores, 64 n per block.
__device__ __forceinline__ void l0_body(const float* __restrict__ X,
                                        const float* __restrict__ W,
                                        const float* __restrict__ bias,
                                        float* __restrict__ OUT, int b) {
    const int o  = threadIdx.x & 31;
    const int ns = threadIdx.x >> 5;   // 0..7
    const int n0 = (b / AB_) * 64;
    const int ab = b % AB_;
    float wv[BIN_];
#pragma unroll
    for (int i = 0; i < BIN_; ++i) wv[i] = W[(ab * BIN_ + i) * BOUT_ + o];
    const float bv = bias[ab * BOUT_ + o];
#pragma unroll
    for (int s = 0; s < 8; ++s) {
        const int n = n0 + ns + s * 8;
        const float* Xp = X + ((size_t)n * AB_ + ab) * BIN_;
        float acc = bv;
#pragma unroll
        for (int i = 0; i < BIN_; ++i) acc = fmaf(Xp[i], wv[i], acc);
        OUT[((size_t)n * AB_ + ab) * BOUT_ + o] = acc;
    }
}

#define NB8 768   // 6144 slices / SPB 8
#define NB6 768
#define NB4 768
#define NB2 768
#define NB0 96

__global__ __launch_bounds__(256, 4)
void s2conv_one(const float* __restrict__ x0, const float* __restrict__ x2,
                const float* __restrict__ x4, const float* __restrict__ x6,
                const float* __restrict__ x8,
                const float* __restrict__ w0, const float* __restrict__ w2,
                const float* __restrict__ w4, const float* __restrict__ w6,
                const float* __restrict__ w8,
                const float* __restrict__ bias, float* __restrict__ out,
                size_t off0, size_t off2, size_t off4, size_t off6, size_t off8) {
    __shared__ __attribute__((aligned(16))) float os[BOUT_ * 17 * 17];  // 37 KB
    int b = blockIdx.x;                        // big degrees first
    if (b < NB8) { mfma_lds_body<17, 8>(x8, w8, out + off8, os, b); return; }
    b -= NB8;
    if (b < NB6) { mfma_lds_body<13, 8>(x6, w6, out + off6, os, b); return; }
    b -= NB6;
    if (b < NB4) { mfma_lds_body< 9, 8>(x4, w4, out + off4, os, b); return; }
    b -= NB4;
    if (b < NB2) { mfma_lds_body< 5, 8>(x2, w2, out + off2, os, b); return; }
    b -= NB2;
    l0_body(x0, w0, bias, out + off0, b);
}

extern "C" void kernel_launch(void* const* d_in, const int* in_sizes, int n_in,
                              void* d_out, int out_size, void* d_ws, size_t ws_size,
                              hipStream_t stream) {
    const float* x0 = (const float*)d_in[0];
    const float* w0 = (const float*)d_in[1];
    const float* x2 = (const float*)d_in[2];
    const float* w2 = (const float*)d_in[3];
    const float* x4 = (const float*)d_in[4];
    const float* w4 = (const float*)d_in[5];
    const float* x6 = (const float*)d_in[6];
    const float* w6 = (const float*)d_in[7];
    const float* x8 = (const float*)d_in[8];
    const float* w8 = (const float*)d_in[9];
    const float* bias = (const float*)d_in[10];
    float* out = (float*)d_out;

    const size_t per = (size_t)B_ * AB_ * BOUT_;
    size_t off0 = 0;
    size_t off2 = off0 + per * 1;
    size_t off4 = off2 + per * 25;
    size_t off6 = off4 + per * 81;
    size_t off8 = off6 + per * 169;

    const int nblocks = NB8 + NB6 + NB4 + NB2 + NB0;   // 3168
    s2conv_one<<<nblocks, 256, 0, stream>>>(x0, x2, x4, x6, x8,
                                            w0, w2, w4, w6, w8,
                                            bias, out,
                                            off0, off2, off4, off6, off8);
}